// Round 1
// baseline (451.608 us; speedup 1.0000x reference)
//
#include <hip/hip_runtime.h>
#include <hip/hip_fp16.h>

#define WAVE 64
constexpr int DH  = 64;    // h feature dim
constexpr int HID = 128;   // MLP hidden
constexpr int NH  = 4;     // heads

// ---------------- uv precompute: u = feat @ W1[0:F], v = feat @ W1[F:2F] ----------------
template<int F, int NB>
__launch_bounds__(256)
__global__ void uv_kernel(const float* __restrict__ feat, const float* __restrict__ w1,
                          __half* __restrict__ u, __half* __restrict__ v, int N) {
  __shared__ float sfeat[NB][F + 1];
  int nb = blockIdx.x * NB;
  for (int i = threadIdx.x; i < NB * F; i += 256) {
    int n = i / F, k = i - n * F;
    int gn = nb + n;
    sfeat[n][k] = (gn < N) ? feat[(size_t)gn * F + k] : 0.f;
  }
  __syncthreads();
  int j = threadIdx.x & 127;
  int g = threadIdx.x >> 7;           // 0..1
  constexpr int NPT = NB / 2;         // nodes per thread
  float ua[NPT], va[NPT];
#pragma unroll
  for (int i = 0; i < NPT; i++) { ua[i] = 0.f; va[i] = 0.f; }
  for (int k = 0; k < F; k++) {
    float wu = w1[k * HID + j];
    float wv = w1[(F + k) * HID + j];
#pragma unroll
    for (int i = 0; i < NPT; i++) {
      float f = sfeat[g * NPT + i][k];
      ua[i] = fmaf(f, wu, ua[i]);
      va[i] = fmaf(f, wv, va[i]);
    }
  }
#pragma unroll
  for (int i = 0; i < NPT; i++) {
    int gn = nb + g * NPT + i;
    if (gn < N) {
      u[(size_t)gn * HID + j] = __float2half(ua[i]);
      v[(size_t)gn * HID + j] = __float2half(va[i]);
    }
  }
}

// ---------------- CSR build ----------------
__global__ void count_kernel(const int* __restrict__ dst, int* __restrict__ counts, int E) {
  int e = blockIdx.x * 256 + threadIdx.x;
  if (e < E) atomicAdd(&counts[dst[e]], 1);
}

__launch_bounds__(1024)
__global__ void scan_kernel(const int* __restrict__ counts, int* __restrict__ offsets, int N, int E) {
  __shared__ int wsum[16];
  __shared__ int carry_s;
  int t = threadIdx.x, lane = t & 63, w = t >> 6;
  if (t == 0) carry_s = 0;
  __syncthreads();
  for (int base = 0; base < N; base += 1024) {
    int idx = base + t;
    int x = (idx < N) ? counts[idx] : 0;
    int v = x;
#pragma unroll
    for (int ofs = 1; ofs < 64; ofs <<= 1) {
      int sl = lane - ofs; if (sl < 0) sl = 0;
      int tv = __shfl(v, sl);
      if (lane >= ofs) v += tv;
    }
    if (lane == 63) wsum[w] = v;
    __syncthreads();
    int wpre = 0;
    for (int ww = 0; ww < w; ww++) wpre += wsum[ww];
    int carry = carry_s;
    int incl = v + wpre;
    if (idx < N) offsets[idx] = carry + incl - x;   // exclusive
    __syncthreads();
    if (t == 1023) carry_s = carry + incl;
    __syncthreads();
  }
  if (t == 0) offsets[N] = E;
}

__global__ void fill_kernel(const int* __restrict__ src, const int* __restrict__ dst,
                            const int* __restrict__ offsets, int* __restrict__ cursor,
                            int* __restrict__ src_sorted, int* __restrict__ dst_sorted, int E) {
  int e = blockIdx.x * 256 + threadIdx.x;
  if (e < E) {
    int d = dst[e];
    int pos = offsets[d] + atomicAdd(&cursor[d], 1);
    src_sorted[pos] = src[e];
    dst_sorted[pos] = d;
  }
}

// ---------------- per-edge scores (lane-per-edge, CSR order) ----------------
struct H8 { __half2 a, b, c, d; };   // 16B = 8 halves

__launch_bounds__(256)
__global__ void score_kernel(const __half* __restrict__ u_pca, const __half* __restrict__ v_pca,
                             const __half* __restrict__ u_pi,  const __half* __restrict__ v_pi,
                             const int* __restrict__ src_sorted, const int* __restrict__ dst_sorted,
                             const float* __restrict__ b1a, const float* __restrict__ w2a, const float* __restrict__ b2a,
                             const float* __restrict__ b1b, const float* __restrict__ w2b, const float* __restrict__ b2b,
                             float* __restrict__ scores, int E) {
  __shared__ float s_w2a[HID * NH], s_w2b[HID * NH], s_b1a[HID], s_b1b[HID], s_b2[8];
  for (int i = threadIdx.x; i < HID * NH; i += 256) { s_w2a[i] = w2a[i]; s_w2b[i] = w2b[i]; }
  for (int i = threadIdx.x; i < HID; i += 256) { s_b1a[i] = b1a[i]; s_b1b[i] = b1b[i]; }
  if (threadIdx.x < 4) s_b2[threadIdx.x] = b2a[threadIdx.x];
  else if (threadIdx.x < 8) s_b2[threadIdx.x] = b2b[threadIdx.x - 4];
  __syncthreads();
  int e = blockIdx.x * 256 + threadIdx.x;
  if (e >= E) return;
  int s = src_sorted[e], d = dst_sorted[e];
  float acc[8];
#pragma unroll
  for (int k = 0; k < 8; k++) acc[k] = s_b2[k];
  // pca attend
  {
    const H8* up = reinterpret_cast<const H8*>(u_pca + (size_t)s * HID);
    const H8* vp = reinterpret_cast<const H8*>(v_pca + (size_t)d * HID);
#pragma unroll
    for (int c = 0; c < HID / 8; c++) {
      H8 uu = up[c], vv = vp[c];
      float2 uf[4] = {__half22float2(uu.a), __half22float2(uu.b), __half22float2(uu.c), __half22float2(uu.d)};
      float2 vf[4] = {__half22float2(vv.a), __half22float2(vv.b), __half22float2(vv.c), __half22float2(vv.d)};
#pragma unroll
      for (int q = 0; q < 4; q++) {
        int j = c * 8 + q * 2;
        float h0 = fmaxf(uf[q].x + vf[q].x + s_b1a[j], 0.f);
        float h1 = fmaxf(uf[q].y + vf[q].y + s_b1a[j + 1], 0.f);
#pragma unroll
        for (int hh = 0; hh < NH; hh++)
          acc[hh] = fmaf(h0, s_w2a[j * NH + hh], fmaf(h1, s_w2a[(j + 1) * NH + hh], acc[hh]));
      }
    }
  }
  // pimg attend
  {
    const H8* up = reinterpret_cast<const H8*>(u_pi + (size_t)s * HID);
    const H8* vp = reinterpret_cast<const H8*>(v_pi + (size_t)d * HID);
#pragma unroll
    for (int c = 0; c < HID / 8; c++) {
      H8 uu = up[c], vv = vp[c];
      float2 uf[4] = {__half22float2(uu.a), __half22float2(uu.b), __half22float2(uu.c), __half22float2(uu.d)};
      float2 vf[4] = {__half22float2(vv.a), __half22float2(vv.b), __half22float2(vv.c), __half22float2(vv.d)};
#pragma unroll
      for (int q = 0; q < 4; q++) {
        int j = c * 8 + q * 2;
        float h0 = fmaxf(uf[q].x + vf[q].x + s_b1b[j], 0.f);
        float h1 = fmaxf(uf[q].y + vf[q].y + s_b1b[j + 1], 0.f);
#pragma unroll
        for (int hh = 0; hh < NH; hh++)
          acc[4 + hh] = fmaf(h0, s_w2b[j * NH + hh], fmaf(h1, s_w2b[(j + 1) * NH + hh], acc[4 + hh]));
      }
    }
  }
  float* op = scores + (size_t)e * 8;
#pragma unroll
  for (int k = 0; k < 8; k++) {
    float v = acc[k];
    op[k] = v > 0.f ? v : 0.01f * v;   // leaky relu
  }
}

// ---------------- softmax + weighted aggregation, one wave per dst node ----------------
__launch_bounds__(256)
__global__ void agg_kernel(const float* __restrict__ scores, const int* __restrict__ src_sorted,
                           const int* __restrict__ offsets, const float* __restrict__ h,
                           float* __restrict__ out, int N) {
  int wid = blockIdx.x * 4 + (threadIdx.x >> 6);
  int lane = threadIdx.x & 63;
  if (wid >= N) return;
  int off0 = offsets[wid], off1 = offsets[wid + 1];
  int deg = off1 - off0;

  float m[8];
#pragma unroll
  for (int k = 0; k < 8; k++) m[k] = -1e30f;
  for (int base = 0; base < deg; base += WAVE) {
    int i = base + lane;
    if (i < deg) {
      const float* sp = scores + (size_t)(off0 + i) * 8;
#pragma unroll
      for (int k = 0; k < 8; k++) m[k] = fmaxf(m[k], sp[k]);
    }
  }
#pragma unroll
  for (int ofs = 32; ofs >= 1; ofs >>= 1) {
#pragma unroll
    for (int k = 0; k < 8; k++) m[k] = fmaxf(m[k], __shfl_xor(m[k], ofs));
  }

  float ssum[8];
#pragma unroll
  for (int k = 0; k < 8; k++) ssum[k] = 0.f;
  for (int base = 0; base < deg; base += WAVE) {
    int i = base + lane;
    if (i < deg) {
      const float* sp = scores + (size_t)(off0 + i) * 8;
#pragma unroll
      for (int k = 0; k < 8; k++) ssum[k] += __expf(sp[k] - m[k]);
    }
  }
#pragma unroll
  for (int ofs = 32; ofs >= 1; ofs >>= 1) {
#pragma unroll
    for (int k = 0; k < 8; k++) ssum[k] += __shfl_xor(ssum[k], ofs);
  }
  float rs[8];
#pragma unroll
  for (int k = 0; k < 8; k++) rs[k] = 1.f / ssum[k];   // deg==0: unused

  float acc[8];
#pragma unroll
  for (int k = 0; k < 8; k++) acc[k] = 0.f;
  for (int base = 0; base < deg; base += WAVE) {
    int i = base + lane;
    float a[8];
    int srcv = 0;
    if (i < deg) {
      srcv = src_sorted[off0 + i];
      const float* sp = scores + (size_t)(off0 + i) * 8;
#pragma unroll
      for (int k = 0; k < 8; k++) a[k] = __expf(sp[k] - m[k]) * rs[k];
    } else {
#pragma unroll
      for (int k = 0; k < 8; k++) a[k] = 0.f;
    }
    int cnt = min(WAVE, deg - base);
    for (int jj = 0; jj < cnt; jj++) {
      int sj = __shfl(srcv, jj);
      float hv = h[(size_t)sj * DH + lane];
#pragma unroll
      for (int k = 0; k < 8; k++) acc[k] = fmaf(__shfl(a[k], jj), hv, acc[k]);
    }
  }
  float* op = out + (size_t)wid * (NH * 2 * DH);
#pragma unroll
  for (int k = 0; k < NH; k++) op[k * 128 + lane] = acc[k];          // pca half
#pragma unroll
  for (int k = 0; k < NH; k++) op[k * 128 + 64 + lane] = acc[k + 4]; // pimg half
}

extern "C" void kernel_launch(void* const* d_in, const int* in_sizes, int n_in,
                              void* d_out, int out_size, void* d_ws, size_t ws_size,
                              hipStream_t stream) {
  const float* h      = (const float*)d_in[0];
  const float* pca    = (const float*)d_in[1];
  const float* pimg   = (const float*)d_in[2];
  const float* pca_w1 = (const float*)d_in[3];
  const float* pca_b1 = (const float*)d_in[4];
  const float* pca_w2 = (const float*)d_in[5];
  const float* pca_b2 = (const float*)d_in[6];
  const float* pi_w1  = (const float*)d_in[7];
  const float* pi_b1  = (const float*)d_in[8];
  const float* pi_w2  = (const float*)d_in[9];
  const float* pi_b2  = (const float*)d_in[10];
  const int*   src    = (const int*)d_in[11];
  const int*   dst    = (const int*)d_in[12];
  int N = in_sizes[0] / 64;
  int E = in_sizes[11];
  float* out = (float*)d_out;

  char* ws = (char*)d_ws;
  size_t o = 0;
  auto alloc = [&](size_t bytes) { void* p = ws + o; o += (bytes + 255) & ~(size_t)255; return p; };
  __half* u_pca = (__half*)alloc((size_t)N * HID * 2);
  __half* v_pca = (__half*)alloc((size_t)N * HID * 2);
  __half* u_pi  = (__half*)alloc((size_t)N * HID * 2);
  __half* v_pi  = (__half*)alloc((size_t)N * HID * 2);
  int* counts   = (int*)alloc((size_t)N * 4);
  int* cursor   = (int*)alloc((size_t)N * 4);
  int* offsets  = (int*)alloc((size_t)(N + 1) * 4);
  int* src_sorted = (int*)alloc((size_t)E * 4);
  int* dst_sorted = (int*)alloc((size_t)E * 4);
  float* scores   = (float*)alloc((size_t)E * 8 * 4);

  hipMemsetAsync(counts, 0, (size_t)N * 4, stream);
  hipMemsetAsync(cursor, 0, (size_t)N * 4, stream);

  uv_kernel<64, 32><<<(N + 31) / 32, 256, 0, stream>>>(pca, pca_w1, u_pca, v_pca, N);
  uv_kernel<32, 32><<<(N + 31) / 32, 256, 0, stream>>>(pimg, pi_w1, u_pi, v_pi, N);
  count_kernel<<<(E + 255) / 256, 256, 0, stream>>>(dst, counts, E);
  scan_kernel<<<1, 1024, 0, stream>>>(counts, offsets, N, E);
  fill_kernel<<<(E + 255) / 256, 256, 0, stream>>>(src, dst, offsets, cursor, src_sorted, dst_sorted, E);
  score_kernel<<<(E + 255) / 256, 256, 0, stream>>>(u_pca, v_pca, u_pi, v_pi, src_sorted, dst_sorted,
                                                    pca_b1, pca_w2, pca_b2, pi_b1, pi_w2, pi_b2, scores, E);
  agg_kernel<<<(N + 3) / 4, 256, 0, stream>>>(scores, src_sorted, offsets, h, out, N);
}